// Round 2
// baseline (442.948 us; speedup 1.0000x reference)
//
#include <hip/hip_runtime.h>
#include <stdint.h>

#define D_MODEL 1024
#define N_HEADS 16
#define D_HEAD  64
#define BATCH   4
#define SEQ     4096
#define BS      (BATCH*SEQ)     // 16384
#define QKV_N   (3*D_MODEL)     // 3072
#define HB      (N_HEADS*BATCH) // 64
#define NCHUNK  8
#define CH_S    (SEQ/NCHUNK)    // 512

using f16x8 = __attribute__((ext_vector_type(8))) _Float16;
using f32x4 = __attribute__((ext_vector_type(4))) float;

__device__ static inline ushort f2h(float f) {
    _Float16 h = (_Float16)f; ushort u; __builtin_memcpy(&u, &h, 2); return u;
}
__device__ static inline float h2f(ushort u) {
    _Float16 h; __builtin_memcpy(&h, &u, 2); return (float)h;
}
__device__ static inline void async16(const ushort* g, ushort* l) {
    __builtin_amdgcn_global_load_lds(
        (const __attribute__((address_space(1))) void*)g,
        (__attribute__((address_space(3))) void*)l, 16, 0, 0);
}

// ---------------- K0: fp32 -> fp16 for x and W in one launch ----------------
__global__ __launch_bounds__(256)
void cvt_both(const float* __restrict__ x, const float* __restrict__ W,
              ushort* __restrict__ xh, ushort* __restrict__ Wh, int nx)
{
    int i = (blockIdx.x * 256 + threadIdx.x) * 8;
    const float* src; ushort* dst; int o;
    if (i < nx) { src = x; dst = xh; o = i; }
    else        { src = W; dst = Wh; o = i - nx; }
    float4 a = *(const float4*)(src + o);
    float4 b = *(const float4*)(src + o + 4);
    *(ushort4*)(dst + o)     = make_ushort4(f2h(a.x),f2h(a.y),f2h(a.z),f2h(a.w));
    *(ushort4*)(dst + o + 4) = make_ushort4(f2h(b.x),f2h(b.y),f2h(b.z),f2h(b.w));
}

// ---------------- K1: 256x256-tile 8-phase pipelined fp16 MFMA GEMM ----------------
// Structure (T1+T2+T3+T4+T5 per the 8-phase template):
//   BM=BN=256, BK=64, 512 threads (8 waves, 2M x 4N), 128 KB LDS, 1 block/CU.
//   LDS = 8 chunks of 16 KB: chunk id = buf*4 + op*2 + khalf, op: A=0/B=1.
//   Each chunk holds 256 rows x 32 cols fp16, organized as [128 row-pairs][8 slots of 16B],
//   slot XOR-swizzled: phys_slot = ((r&1)*4 + k4) ^ ((r>>1)&7).
//   -> ds_read_b128 fragment reads are bank-conflict-free (every 8-lane group
//      covering one row-pair group hits all 8 phys slots = all 32 banks); global
//      source is pre-swizzled so global_load_lds dests stay linear (rule #21).
//   K-loop: 16 K-tiles, 2 per iteration, 8 phases/iter, each phase =
//   {8 ds_read_b128; 1 chunk stage (2 global_load_lds_dwordx4); barrier;
//    setprio(1); 16 MFMA; setprio(0); lgkm drain; [vmcnt(4) @ p4,p8]; barrier}.
//   Stage schedule (chunk <- content):
//     p1: ch5<-A(kt1,k1)  p2: ch7<-B(kt1,k1)  p3: ch0<-A(kt0+2,k0)  p4: ch2<-B(kt0+2,k0)
//     p5: ch1<-A(kt0+2,k1) p6: ch3<-B(kt0+2,k1) p7: ch4<-A(kt0+3,k0) p8: ch6<-B(kt0+3,k0)
//   vmcnt(4) @p4 leaves only p3/p4's loads in flight -> chunks read at p5-p8 landed.
//   vmcnt(4) @p8 leaves only p7/p8's loads -> chunks read at next-iter p1-p4 landed.
// v-type waves compute mfma(B,A) (transposed D) so v stores are ushort4 like q/k.
#define MF(a,b,c) __builtin_amdgcn_mfma_f32_16x16x32_f16(a,b,c,0,0,0)
#define FENCE asm volatile("" ::: "memory")
#define VM4 asm volatile("s_waitcnt vmcnt(4)" ::: "memory")
#define VM0 asm volatile("s_waitcnt vmcnt(0)" ::: "memory")
#define VMN do {} while (0)
#define NOSTAGE do {} while (0)

#define STAGE(CH, S0, S1, KC) do { \
    async16((S0) + (KC), &lds[(CH)*8192 + d0]); \
    async16((S1) + (KC), &lds[(CH)*8192 + d1]); } while (0)

#define MROW(AI, I) \
    acc[(I)*4+0]=MF(AI,b0,acc[(I)*4+0]); \
    acc[(I)*4+1]=MF(AI,b1,acc[(I)*4+1]); \
    acc[(I)*4+2]=MF(AI,b2,acc[(I)*4+2]); \
    acc[(I)*4+3]=MF(AI,b3,acc[(I)*4+3]);

#define MROWS(AI, I) \
    acc[(I)*4+0]=MF(b0,AI,acc[(I)*4+0]); \
    acc[(I)*4+1]=MF(b1,AI,acc[(I)*4+1]); \
    acc[(I)*4+2]=MF(b2,AI,acc[(I)*4+2]); \
    acc[(I)*4+3]=MF(b3,AI,acc[(I)*4+3]);

#define PHASE(CA, CB, IH, STG, VMW) do { \
    const ushort* pa = &lds[(CA)*8192 + aoff]; \
    const ushort* pb = &lds[(CB)*8192 + boff]; \
    f16x8 a0 = *(const f16x8*)(pa + ((IH)*4+0)*512); \
    f16x8 a1 = *(const f16x8*)(pa + ((IH)*4+1)*512); \
    f16x8 a2 = *(const f16x8*)(pa + ((IH)*4+2)*512); \
    f16x8 a3 = *(const f16x8*)(pa + ((IH)*4+3)*512); \
    f16x8 b0 = *(const f16x8*)(pb + 0*512); \
    f16x8 b1 = *(const f16x8*)(pb + 1*512); \
    f16x8 b2 = *(const f16x8*)(pb + 2*512); \
    f16x8 b3 = *(const f16x8*)(pb + 3*512); \
    STG; \
    FENCE; __builtin_amdgcn_s_barrier(); FENCE; \
    __builtin_amdgcn_s_setprio(1); \
    if (!isV) { \
        MROW(a0,(IH)*4+0) MROW(a1,(IH)*4+1) MROW(a2,(IH)*4+2) MROW(a3,(IH)*4+3) \
    } else { \
        MROWS(a0,(IH)*4+0) MROWS(a1,(IH)*4+1) MROWS(a2,(IH)*4+2) MROWS(a3,(IH)*4+3) \
    } \
    __builtin_amdgcn_s_setprio(0); \
    asm volatile("s_waitcnt lgkmcnt(0)" ::: "memory"); \
    VMW; \
    FENCE; __builtin_amdgcn_s_barrier(); FENCE; \
  } while (0)

__global__ __launch_bounds__(512, 2)
void qkv_gemm_f16(const ushort* __restrict__ Ah, const ushort* __restrict__ Bh,
                  const float* __restrict__ bias,
                  ushort* __restrict__ qh, ushort* __restrict__ kh,
                  ushort* __restrict__ varr)
{
    __shared__ ushort lds[8 * 8192];   // 128 KB
    const int t = threadIdx.x;
    const int lane = t & 63, w = t >> 6;

    // XCD-aware bijective block swizzle (768 blocks, 768%8==0): each XCD gets a
    // contiguous band of blockIdx.y (A-panel reuse inside one XCD's L2).
    const int id0 = blockIdx.y * 12 + blockIdx.x;
    const int ids = (id0 & 7) * 96 + (id0 >> 3);
    const int n0 = (ids % 12) * 256;
    const int m0 = (ids / 12) * 256;

    const int wm = (w >> 2) * 128;     // wave's M offset (2 waves in M)
    const int wn = (w & 3) * 64;       // wave's N offset (4 waves in N)
    const int fr = lane & 15;
    const int hq = lane >> 4;

    // staging: 2 loads/thread per 16KB chunk; unit u -> row-pair rp=u>>3, phys slot u&7;
    // source is pre-swizzled: logical slot8 = phys ^ (rp&7); row = rp*2 + (slot8>>2),
    // col-slot k4 = slot8&3.
    const int u0 = t, u1 = 512 + t;
    const int rp0 = u0 >> 3, rp1 = u1 >> 3;
    const int sl0 = (u0 & 7) ^ (rp0 & 7), sl1 = (u1 & 7) ^ (rp1 & 7);
    const int r0 = rp0 * 2 + (sl0 >> 2), r1 = rp1 * 2 + (sl1 >> 2);
    const int c0 = (sl0 & 3) * 8,        c1 = (sl1 & 3) * 8;
    const ushort* aS0 = Ah + (size_t)(m0 + r0) * D_MODEL + c0;
    const ushort* aS1 = Ah + (size_t)(m0 + r1) * D_MODEL + c1;
    const ushort* bS0 = Bh + (size_t)(n0 + r0) * D_MODEL + c0;
    const ushort* bS1 = Bh + (size_t)(n0 + r1) * D_MODEL + c1;
    const int d0 = w * 512;            // LDS ushort offset in chunk, load 0 (wave-uniform)
    const int d1 = 4096 + w * 512;     // load 1

    // fragment-read offset (lane-constant): row = base + fr, k-slot = hq;
    // rp&7 == (fr>>1)&7 because wm, i*16 contribute multiples of 8 row-pairs.
    const int rdo  = ((fr >> 1) * 64) + ((((fr & 1) * 4 + hq) ^ ((fr >> 1) & 7)) * 8);
    const int aoff = wm * 32 + rdo;
    const int boff = wn * 32 + rdo;

    const int cgb = n0 + wn;                    // 64-aligned output-column base
    const int typ = __builtin_amdgcn_readfirstlane((cgb % 192) / 64); // 0=q,1=k,2=v
    const bool isV = (typ == 2);

    f32x4 acc[32] = {};   // q/k: acc[i*4+j] = D[s-tile i][ci-tile j]; v: transposed

    // ---- prologue: kt0 (all 4 chunks) + kt1 (k0 chunks); drain to last 4 ----
    STAGE(0, aS0, aS1, 0);
    STAGE(2, bS0, bS1, 0);
    STAGE(1, aS0, aS1, 32);
    STAGE(3, bS0, bS1, 32);
    STAGE(4, aS0, aS1, 64);
    STAGE(6, bS0, bS1, 64);
    VM4;
    __builtin_amdgcn_s_barrier();
    FENCE;

    #pragma unroll 1
    for (int it = 0; it < 7; ++it) {
        const int kb = it * 128;
        PHASE(0,2,0, STAGE(5, aS0,aS1, kb+96),  VMN);
        PHASE(0,2,1, STAGE(7, bS0,bS1, kb+96),  VMN);
        PHASE(1,3,0, STAGE(0, aS0,aS1, kb+128), VMN);
        PHASE(1,3,1, STAGE(2, bS0,bS1, kb+128), VM4);
        PHASE(4,6,0, STAGE(1, aS0,aS1, kb+160), VMN);
        PHASE(4,6,1, STAGE(3, bS0,bS1, kb+160), VMN);
        PHASE(5,7,0, STAGE(4, aS0,aS1, kb+192), VMN);
        PHASE(5,7,1, STAGE(6, bS0,bS1, kb+192), VM4);
    }
    // ---- tail iteration (kt0=14, kt1=15): only kt1's k1 chunks still to stage ----
    PHASE(0,2,0, STAGE(5, aS0,aS1, 992), VMN);
    PHASE(0,2,1, STAGE(7, bS0,bS1, 992), VMN);
    PHASE(1,3,0, NOSTAGE, VMN);
    PHASE(1,3,1, NOSTAGE, VM0);
    PHASE(4,6,0, NOSTAGE, VMN);
    PHASE(4,6,1, NOSTAGE, VMN);
    PHASE(5,7,0, NOSTAGE, VMN);
    PHASE(5,7,1, NOSTAGE, VMN);

    // ---- epilogue: C/D row=(lane>>4)*4+r, col=lane&15 (validated) ----
    const int col = lane & 15, rq = (lane >> 4) * 4;
    const int h   = cgb / 192;
    const int b   = m0 >> 12;
    const int sbl = (m0 & 4095) + wm;

    if (typ < 2) {
        ushort* dst = typ ? kh : qh;
        #pragma unroll
        for (int j = 0; j < 4; ++j) {
            const int ci = j*16 + col;
            const float bj = bias[cgb + ci];
            const size_t rowoff = ((size_t)(h*4 + b)*64 + ci) * SEQ;
            #pragma unroll
            for (int i = 0; i < 8; ++i) {
                const int s0 = sbl + i*16 + rq;            // multiple of 4
                float v0 = acc[i*4+j][0] + bj, v1 = acc[i*4+j][1] + bj;
                float v2 = acc[i*4+j][2] + bj, v3 = acc[i*4+j][3] + bj;
                if (s0 < 32) {
                    // RoPE: pairs (s0,s0+1) m=s0/2 and (s0+2,s0+3) m=s0/2+1,
                    // angle = ci * 10000^(-m/16)
                    int mp = s0 >> 1;
                    float if0 = powf(10000.0f, -(float)mp / 16.0f);
                    float if1 = powf(10000.0f, -(float)(mp + 1) / 16.0f);
                    float a0 = (float)ci * if0, a1 = (float)ci * if1;
                    float cc0 = cosf(a0), s0n = sinf(a0);
                    float cc1 = cosf(a1), s1n = sinf(a1);
                    float n0_ = v0*cc0 - v1*s0n, n1_ = v1*cc0 + v0*s0n;
                    float n2_ = v2*cc1 - v3*s1n, n3_ = v3*cc1 + v2*s1n;
                    v0 = n0_; v1 = n1_; v2 = n2_; v3 = n3_;
                }
                *(ushort4*)&dst[rowoff + s0] = make_ushort4(
                    f2h(v0), f2h(v1), f2h(v2), f2h(v3));
            }
        }
    } else {
        // swapped-operand acc: acc[i*4+j][r] is at ci = j*16+rq+r, s = sbl+i*16+col
        const size_t base = (size_t)(h*4 + b) * SEQ;
        #pragma unroll
        for (int j = 0; j < 4; ++j) {
            const float4 b4 = *(const float4*)&bias[cgb + j*16 + rq];
            #pragma unroll
            for (int i = 0; i < 8; ++i) {
                const int s = sbl + i*16 + col;
                *(ushort4*)&varr[(base + s)*64 + j*16 + rq] = make_ushort4(
                    f2h(acc[i*4+j][0] + b4.x), f2h(acc[i*4+j][1] + b4.y),
                    f2h(acc[i*4+j][2] + b4.z), f2h(acc[i*4+j][3] + b4.w));
            }
        }
    }
}

// ---------------- K2: partial scores (MFMA) per K-chunk ----------------
// partial[hb][chunk][d][e] = sum_{s in chunk} q[d,s]*k[e,s]
__global__ __launch_bounds__(256)
void scores_partial(const ushort* __restrict__ qh, const ushort* __restrict__ kh,
                    float* __restrict__ partial)
{
    __shared__ float L[4 * 4096];   // 64 KB: per-wave 64x64 partials
    const int t = threadIdx.x, lane = t & 63, w = t >> 6;
    const int hb = blockIdx.x, chunk = blockIdx.y;
    const ushort* qb = qh + (size_t)hb * 64 * SEQ;
    const ushort* kb = kh + (size_t)hb * 64 * SEQ;
    const int fr = lane & 15, fq = (lane >> 4) * 8;

    f32x4 acc[4][4] = {};
    const int kbase = chunk * CH_S + w * (CH_S / 4);
    for (int kk = 0; kk < CH_S / 4; kk += 32) {
        const int k0 = kbase + kk;
        f16x8 af[4], bf[4];
        #pragma unroll
        for (int i = 0; i < 4; ++i)
            af[i] = *(const f16x8*)&qb[(size_t)(i*16 + fr) * SEQ + k0 + fq];
        #pragma unroll
        for (int j = 0; j < 4; ++j)
            bf[j] = *(const f16x8*)&kb[(size_t)(j*16 + fr) * SEQ + k0 + fq];
        #pragma unroll
        for (int i = 0; i < 4; ++i)
            #pragma unroll
            for (int j = 0; j < 4; ++j)
                acc[i][j] = __builtin_amdgcn_mfma_f32_16x16x32_f16(
                                af[i], bf[j], acc[i][j], 0, 0, 0);
    }

    float* Lw = &L[w * 4096];
    const int col = lane & 15, rq = (lane >> 4) * 4;
    #pragma unroll
    for (int i = 0; i < 4; ++i)
        #pragma unroll
        for (int j = 0; j < 4; ++j)
            #pragma unroll
            for (int r = 0; r < 4; ++r)
                Lw[(i*16 + rq + r)*64 + j*16 + col] = acc[i][j][r];
    __syncthreads();

    // reduce 4 wave-partials and write to global (float4, coalesced)
    float* pb = partial + ((size_t)hb * NCHUNK + chunk) * 4096;
    #pragma unroll
    for (int u = 0; u < 4; ++u) {
        int idx = u*1024 + t*4;
        f32x4 s = *(f32x4*)&L[idx];
        s += *(f32x4*)&L[4096 + idx];
        s += *(f32x4*)&L[8192 + idx];
        s += *(f32x4*)&L[12288 + idx];
        *(f32x4*)&pb[idx] = s;
    }
}

// ---------------- K3: sum chunks, softmax over e; P fp16 [d][e] ----------------
__global__ __launch_bounds__(256)
void softmax_k(const float* __restrict__ partial, ushort* __restrict__ Pt)
{
    __shared__ float L[64 * 65];   // padded: row d at L[d*65]
    const int t = threadIdx.x;
    const int hb = blockIdx.x;
    const float* pb = partial + (size_t)hb * NCHUNK * 4096;

    #pragma unroll
    for (int u = 0; u < 16; ++u) {
        int idx = u*256 + t;              // coalesced global reads
        float s = 0.f;
        #pragma unroll
        for (int c = 0; c < NCHUNK; ++c) s += pb[c*4096 + idx];
        L[(idx >> 6) * 65 + (idx & 63)] = s;
    }
    __syncthreads();

    if (t < 64) {
        float* row = &L[t * 65];          // stride 65: conflict-free across lanes
        float mx = -1e30f;
        for (int e = 0; e < 64; ++e) mx = fmaxf(mx, row[e]);
        float sum = 0.f;
        for (int e = 0; e < 64; ++e) {
            float v = expf(0.125f * (row[e] - mx));
            row[e] = v; sum += v;
        }
        float inv = 1.f / sum;
        ushort* pd = Pt + (size_t)hb * 4096 + t * 64;
        for (int e = 0; e < 64; ++e) pd[e] = f2h(row[e] * inv);
    }
}

// ---------------- K4: out^T[s][d] = sum_e v[s][e] * P[d][e]  (MFMA, K=64) ----------------
__global__ __launch_bounds__(256)
void attn_out_mfma(const ushort* __restrict__ varr, const ushort* __restrict__ Pt,
                   float* __restrict__ out)
{
    const int t = threadIdx.x, lane = t & 63, w = t >> 6;
    const int hb = blockIdx.x;
    const int sb = blockIdx.y * 256 + w * 64;
    const int fr = lane & 15, fq = (lane >> 4) * 8;

    const ushort* Pb = Pt + (size_t)hb * 4096;
    const ushort* vb = varr + (size_t)hb * SEQ * 64;

    f16x8 aV[4][2], bP[4][2];
    #pragma unroll
    for (int i = 0; i < 4; ++i)
        #pragma unroll
        for (int ks = 0; ks < 2; ++ks)
            aV[i][ks] = *(const f16x8*)&vb[(size_t)(sb + i*16 + fr)*64 + ks*32 + fq];
    #pragma unroll
    for (int j = 0; j < 4; ++j)
        #pragma unroll
        for (int ks = 0; ks < 2; ++ks)
            bP[j][ks] = *(const f16x8*)&Pb[(j*16 + fr)*64 + ks*32 + fq];

    f32x4 acc[4][4] = {};   // [s-tile][d-tile]
    #pragma unroll
    for (int ks = 0; ks < 2; ++ks)
        #pragma unroll
        for (int i = 0; i < 4; ++i)
            #pragma unroll
            for (int j = 0; j < 4; ++j)
                acc[i][j] = __builtin_amdgcn_mfma_f32_16x16x32_f16(
                                aV[i][ks], bP[j][ks], acc[i][j], 0, 0, 0);

    // D[m=s][n=d]: regs r are 4 consecutive s -> float4 stores along s
    const int col = lane & 15, rq = (lane >> 4) * 4;
    const int h = hb >> 2, b = hb & 3;
    #pragma unroll
    for (int i = 0; i < 4; ++i)
        #pragma unroll
        for (int j = 0; j < 4; ++j) {
            const int dg = j*16 + col;
            size_t off = (((size_t)h*64 + dg)*4 + b)*SEQ + sb + i*16 + rq;
            *(float4*)&out[off] = make_float4(acc[i][j][0], acc[i][j][1],
                                              acc[i][j][2], acc[i][j][3]);
        }
}

// ---------------- launcher ----------------
extern "C" void kernel_launch(void* const* d_in, const int* in_sizes, int n_in,
                              void* d_out, int out_size, void* d_ws, size_t ws_size,
                              hipStream_t stream)
{
    const float* x    = (const float*)d_in[0];
    const float* W    = (const float*)d_in[1];
    const float* bias = (const float*)d_in[2];
    float* out = (float*)d_out;

    char* p = (char*)d_ws;
    ushort* qh   = (ushort*)p;  p += (size_t)HB * 64 * SEQ * 2;        // 33.6 MB
    ushort* kh   = (ushort*)p;  p += (size_t)HB * 64 * SEQ * 2;        // 33.6 MB
    ushort* varr = (ushort*)p;  p += (size_t)HB * SEQ * 64 * 2;        // 33.6 MB
    ushort* Pth  = (ushort*)p;  p += (size_t)HB * 4096 * 2;            //  0.5 MB
    float* partial = (float*)p; p += (size_t)HB * NCHUNK * 4096 * 4;   //  8.4 MB
    ushort* xh   = (ushort*)p;  p += (size_t)BS * D_MODEL * 2;         // 33.6 MB
    ushort* Wh   = (ushort*)p;  p += (size_t)QKV_N * D_MODEL * 2;      //  6.3 MB

    const int nx = BS * D_MODEL;       // 16777216
    const int nw = QKV_N * D_MODEL;    // 3145728
    cvt_both<<<(nx + nw)/2048, 256, 0, stream>>>(x, W, xh, Wh, nx);

    qkv_gemm_f16<<<dim3(QKV_N/256, BS/256), 512, 0, stream>>>(
        xh, Wh, bias, qh, kh, varr);

    scores_partial<<<dim3(HB, NCHUNK), 256, 0, stream>>>(qh, kh, partial);
    softmax_k<<<HB, 256, 0, stream>>>(partial, Pth);
    attn_out_mfma<<<dim3(HB, 16), 256, 0, stream>>>(varr, Pth, out);
}